// Round 2
// baseline (376.862 us; speedup 1.0000x reference)
//
#include <hip/hip_runtime.h>
#include <hip/hip_bf16.h>

// ---------- types ----------
typedef unsigned short bfu;                                        // bf16 bit-pattern storage
typedef short          bf16x8 __attribute__((ext_vector_type(8))); // MFMA A/B frag (4 VGPRs)
typedef float          floatx4 __attribute__((ext_vector_type(4)));// MFMA C/D frag
typedef unsigned short bfu4 __attribute__((ext_vector_type(4)));   // 8B packed store
typedef unsigned int   u32x2 __attribute__((ext_vector_type(2)));  // 8B LDS write

__device__ __forceinline__ bfu f2bf(float f) {
    __hip_bfloat16 h = __float2bfloat16(f);   // RNE
    return __builtin_bit_cast(unsigned short, h);
}

// async global->LDS, 16B per lane; lds base must be wave-uniform (HW adds lane*16)
__device__ __forceinline__ void glds16(const bfu* g, bfu* l) {
    __builtin_amdgcn_global_load_lds(
        (const __attribute__((address_space(1))) unsigned int*)g,
        (__attribute__((address_space(3))) unsigned int*)l, 16, 0, 0);
}

// ---------- problem constants ----------
#define BATCH 2
#define SEQ   2048
#define DM    2048
#define NH    16
#define DKH   128
#define SCALE 0.08838834764831845f   // 1/sqrt(128)

// =====================================================================
// convert x (f32) -> xb (bf16), 4 elems/thread
// =====================================================================
__global__ __launch_bounds__(256)
void cvt_x(const float* __restrict__ x, bfu* __restrict__ xb, int n) {
    const int i = (blockIdx.x * 256 + threadIdx.x) * 4;
    if (i >= n) return;
    const float4 v = *(const float4*)(x + i);
    bfu4 p; p[0] = f2bf(v.x); p[1] = f2bf(v.y); p[2] = f2bf(v.z); p[3] = f2bf(v.w);
    *(bfu4*)(xb + i) = p;
}

// =====================================================================
// batched transpose + f32->bf16 convert + scale (WO)
// =====================================================================
__global__ __launch_bounds__(256)
void tcvt(const float* __restrict__ in, bfu* __restrict__ out, int R, int C, float s) {
    __shared__ float tile[32][33];
    const int bz = blockIdx.z;
    const float* src = in + (size_t)bz * R * C;
    bfu* dst = out + (size_t)bz * R * C;
    const int c0 = blockIdx.x * 32, r0 = blockIdx.y * 32;
    const int tx = threadIdx.x, ty = threadIdx.y;
    #pragma unroll
    for (int i = 0; i < 4; i++)
        tile[ty + i*8][tx] = src[(size_t)(r0 + ty + i*8) * C + c0 + tx];
    __syncthreads();
    #pragma unroll
    for (int i = 0; i < 4; i++)
        dst[(size_t)(c0 + ty + i*8) * R + r0 + tx] = f2bf(tile[tx][ty + i*8] * s);
}

// =====================================================================
// fused Q/K/V weight transpose+convert: grid (4, 64, 48), block (32,8)
// =====================================================================
__global__ __launch_bounds__(256)
void tcvt_qkv(const float* __restrict__ WQ, const float* __restrict__ WK,
              const float* __restrict__ WV,
              bfu* __restrict__ WtQ, bfu* __restrict__ WtK, bfu* __restrict__ WtV) {
    __shared__ float tile[32][33];
    const int p  = blockIdx.z >> 4;
    const int bz = blockIdx.z & 15;
    const float* src = (p == 0) ? WQ : (p == 1) ? WK : WV;
    bfu*         dst = (p == 0) ? WtQ : (p == 1) ? WtK : WtV;
    const float  s   = (p == 0) ? SCALE : 1.0f;
    src += (size_t)bz * DM * DKH;
    dst += (size_t)bz * DM * DKH;
    const int c0 = blockIdx.x * 32, r0 = blockIdx.y * 32;
    const int tx = threadIdx.x, ty = threadIdx.y;
    #pragma unroll
    for (int i = 0; i < 4; i++)
        tile[ty + i*8][tx] = src[(size_t)(r0 + ty + i*8) * DKH + c0 + tx];
    __syncthreads();
    #pragma unroll
    for (int i = 0; i < 4; i++)
        dst[(size_t)(c0 + ty + i*8) * DM + r0 + tx] = f2bf(tile[tx][ty + i*8] * s);
}

// =====================================================================
// 8-phase 256x256 GEMM helpers (T2 st_16x32 swizzle, T3/T4 counted vmcnt,
// T5 setprio).  Half-tile = [128 rows][64 cols] bf16, stored as 16x32
// subtiles (1024B): elem(r,c) = ((r>>4)*2+(c>>5))*512 + (r&15)*32
//                               + ((c&31) ^ ((r&8)?16:0))
// Stage keeps the LDS dest LINEAR (global_load_lds) and inverse-swizzles
// the per-lane GLOBAL source; reader applies the same XOR -> identity.
// =====================================================================
__device__ __forceinline__ void stg_half(const bfu* gbase, bfu* slot,
                                         int wave, int lane, int csw) {
    #pragma unroll
    for (int l = 0; l < 2; l++) {
        const int j = l * 8 + wave;                         // wave-issue id 0..15
        glds16(gbase + (size_t)((j >> 1) * 16 + (lane >> 2)) * DM
                     + (j & 1) * 32 + csw,
               slot + j * 512);
    }
}

__device__ __forceinline__ void ld_b8(bf16x8 (&bv)[4][2], const bfu* slot, int rdo) {
    #pragma unroll
    for (int n = 0; n < 4; n++)
        #pragma unroll
        for (int ks = 0; ks < 2; ks++)
            bv[n][ks] = *(const bf16x8*)&slot[(n * 2 + ks) * 512 + rdo];
}

__device__ __forceinline__ void ld_a8(bf16x8 (&af)[4][2], const bfu* slot, int rdo) {
    #pragma unroll
    for (int m = 0; m < 4; m++)
        #pragma unroll
        for (int ks = 0; ks < 2; ks++)
            af[m][ks] = *(const bf16x8*)&slot[(m * 2 + ks) * 512 + rdo];
}

template<int MH, int NHALF>
__device__ __forceinline__ void mfma16(floatx4 (&acc)[8][4],
                                       const bf16x8 (&af)[4][2],
                                       const bf16x8 (&bv)[4][2]) {
    __builtin_amdgcn_s_setprio(1);
    #pragma unroll
    for (int m = 0; m < 4; m++)
        #pragma unroll
        for (int n = 0; n < 2; n++)
            #pragma unroll
            for (int ks = 0; ks < 2; ks++)
                acc[MH*4 + m][NHALF*2 + n] =
                    __builtin_amdgcn_mfma_f32_16x16x32_bf16(
                        af[m][ks], bv[NHALF*2 + n][ks],
                        acc[MH*4 + m][NHALF*2 + n], 0, 0, 0);
    __builtin_amdgcn_s_setprio(0);
}

#define BARW()                                                      \
    __builtin_amdgcn_s_barrier();                                   \
    asm volatile("s_waitcnt lgkmcnt(0)" ::: "memory");              \
    __builtin_amdgcn_sched_barrier(0)

// =====================================================================
// fused QKV projection, 256^2 8-phase: grid (16, 24), block 512 (8 waves)
// by = p*8 + n-tile.  p 0: Q->Qall (bf16 rm), 1: K->Kall, 2: V->Vt
// =====================================================================
__global__ __launch_bounds__(512, 2)
void proj_qkv8(const bfu* __restrict__ xb,
               const bfu* __restrict__ WtQ, const bfu* __restrict__ WtK,
               const bfu* __restrict__ WtV,
               const float* __restrict__ bQ, const float* __restrict__ bK,
               const float* __restrict__ bV,
               bfu* __restrict__ Qall, bfu* __restrict__ Kall, bfu* __restrict__ Vt) {
    __shared__ __align__(16) bfu As[2][2][8192];   // [buf][half][128*64]
    __shared__ __align__(16) bfu Bs[2][2][8192];

    const int p = blockIdx.y >> 3;
    const bfu*   Wt   = (p == 0) ? WtQ : (p == 1) ? WtK : WtV;
    const float* bias = (p == 0) ? bQ  : (p == 1) ? bK  : bV;
    const float  bscale = (p == 0) ? SCALE : 1.0f;

    const int tid  = threadIdx.x;
    const int lane = tid & 63;
    const int wave = tid >> 6;
    const int lrow = lane & 15;
    const int quad = lane >> 4;
    const int wr   = wave >> 2;            // 0..1 : M half (128 rows)
    const int wc   = wave & 3;             // 0..3 : N quarter (64 cols)
    const size_t m0 = (size_t)blockIdx.x * 256;
    const int    n0 = (int)(blockIdx.y & 7) * 256;

    // stage: per-lane inverse-swizzled global col offset (elements)
    const int csw = ((lane & 3) * 8) ^ ((lane & 32) ? 16 : 0);
    // read: swizzled offset within a (16-row x 32-col) subtile pair
    const int rdo = lrow * 32 + ((quad * 8) ^ ((lrow & 8) ? 16 : 0));

    const bfu* Ab = xb + m0 * DM;
    const bfu* Bb = Wt + (size_t)n0 * DM;

    floatx4 acc[8][4] = {};
    bf16x8 af[4][2], bv[4][2];

#define STAGE_A(tau, h)                                                     \
    if ((tau) < 32) stg_half(Ab + (size_t)((h) * 128) * DM + (tau) * 64,    \
                             &As[(tau) & 1][h][0], wave, lane, csw)
#define STAGE_B(tau, h)                                                     \
    if ((tau) < 32) stg_half(Bb + (size_t)((h) * 128) * DM + (tau) * 64,    \
                             &Bs[(tau) & 1][h][0], wave, lane, csw)

    // ---- prologue: 7 half-tiles (K-tile 0 + 3/4 of K-tile 1) ----
    STAGE_B(0, 0); STAGE_B(0, 1); STAGE_A(0, 0); STAGE_A(0, 1);
    STAGE_B(1, 0); STAGE_B(1, 1); STAGE_A(1, 0);
    asm volatile("s_waitcnt vmcnt(6)" ::: "memory");
    __builtin_amdgcn_s_barrier();

    #pragma unroll 1
    for (int i = 0; i < 16; i++) {
        const int t0 = 2 * i;
        // ======== K-tile t0 (buf 0) ========
        // phase 0: read all-B + A(mh0); stage A(t0+1) h1 (-> buf1)
        ld_b8(bv, &Bs[0][wc >> 1][(wc & 1) * 4096], rdo);
        ld_a8(af, &As[0][wr][0], rdo);
        STAGE_A(t0 + 1, 1);
        BARW();
        mfma16<0, 0>(acc, af, bv);
        __builtin_amdgcn_s_barrier();
        // phase 1: stage B(t0+2) h0
        STAGE_B(t0 + 2, 0);
        BARW();
        mfma16<0, 1>(acc, af, bv);
        __builtin_amdgcn_s_barrier();
        // phase 2: read A(mh1); stage B(t0+2) h1
        ld_a8(af, &As[0][wr][4096], rdo);
        STAGE_B(t0 + 2, 1);
        BARW();
        mfma16<1, 0>(acc, af, bv);
        __builtin_amdgcn_s_barrier();
        // phase 3: stage A(t0+2) h0; counted vmcnt -> buf1 ready
        STAGE_A(t0 + 2, 0);
        BARW();
        mfma16<1, 1>(acc, af, bv);
        if (i == 15) asm volatile("s_waitcnt vmcnt(0)" ::: "memory");
        else         asm volatile("s_waitcnt vmcnt(6)" ::: "memory");
        __builtin_amdgcn_s_barrier();
        // ======== K-tile t0+1 (buf 1) ========
        // phase 4: read all-B + A(mh0) from buf1; stage A(t0+2) h1
        ld_b8(bv, &Bs[1][wc >> 1][(wc & 1) * 4096], rdo);
        ld_a8(af, &As[1][wr][0], rdo);
        STAGE_A(t0 + 2, 1);
        BARW();
        mfma16<0, 0>(acc, af, bv);
        __builtin_amdgcn_s_barrier();
        // phase 5: stage B(t0+3) h0
        STAGE_B(t0 + 3, 0);
        BARW();
        mfma16<0, 1>(acc, af, bv);
        __builtin_amdgcn_s_barrier();
        // phase 6: read A(mh1) buf1; stage B(t0+3) h1
        ld_a8(af, &As[1][wr][4096], rdo);
        STAGE_B(t0 + 3, 1);
        BARW();
        mfma16<1, 0>(acc, af, bv);
        __builtin_amdgcn_s_barrier();
        // phase 7: stage A(t0+3) h0; counted vmcnt -> buf0 ready
        STAGE_A(t0 + 3, 0);
        BARW();
        mfma16<1, 1>(acc, af, bv);
        if (i < 15) asm volatile("s_waitcnt vmcnt(6)" ::: "memory");
        __builtin_amdgcn_s_barrier();
    }
#undef STAGE_A
#undef STAGE_B

    // ---- epilogue (C/D: col = lane&15 -> n, row = quad*4+r -> m) ----
    if (p < 2) {
        bfu* Out = (p == 0) ? Qall : Kall;
        #pragma unroll
        for (int m = 0; m < 8; m++) {
            #pragma unroll
            for (int n = 0; n < 4; n++) {
                const int gn = n0 + wc * 64 + n * 16 + lrow;
                const float bvv = bias[gn] * bscale;
                #pragma unroll
                for (int r = 0; r < 4; r++) {
                    const size_t gm = m0 + wr * 128 + m * 16 + quad * 4 + r;
                    Out[gm * DM + gn] = f2bf(acc[m][n][r] + bvv);
                }
            }
        }
    } else {
        #pragma unroll
        for (int m = 0; m < 8; m++) {
            #pragma unroll
            for (int n = 0; n < 4; n++) {
                const int gn = n0 + wc * 64 + n * 16 + lrow;
                const float bvv = bias[gn];
                const size_t gm0 = m0 + wr * 128 + m * 16 + quad * 4;
                const int b = (int)(gm0 >> 11), s = (int)(gm0 & 2047);
                bfu4 pk;
                #pragma unroll
                for (int r = 0; r < 4; r++) pk[r] = f2bf(acc[m][n][r] + bvv);
                *(bfu4*)&Vt[((size_t)(b * NH + (gn >> 7)) * DKH + (gn & 127)) * SEQ + s] = pk;
            }
        }
    }
}

// =====================================================================
// causal flash attention (swapped QK^T, packed P-writes) — unchanged
// =====================================================================
__global__ __launch_bounds__(256)
void flash_attn(const bfu* __restrict__ Q, const bfu* __restrict__ K,
                const bfu* __restrict__ Vt, bfu* __restrict__ Z) {
    __shared__ bfu Ks[4][64][32];    // [kc][key][32 k-elems] : 16 KB, 64B rows
    __shared__ bfu Vs[2][128][32];   // [s-half][dk][32 s]    : 16 KB, 64B rows
    __shared__ bfu Ps[4][16][72];    // per wave [q][64 s + 8 pad] : 9 KB, 144B rows

    const int tid  = threadIdx.x;
    const int lane = tid & 63;
    const int wave = tid >> 6;
    const int lrow = lane & 15;
    const int quad = lane >> 4;
    const int hb = blockIdx.x;
    const int h = hb & 15, b = hb >> 4;
    const int qt = 31 - blockIdx.y;            // heavy blocks first
    const int q0w = qt * 64 + wave * 16;
    const int rowb = lane >> 2, colb = (lane & 3) * 8;

    const bfu* Qrow = Q + (size_t)(b * SEQ + q0w + lrow) * DM + h * DKH;
    bf16x8 qf[4];
    #pragma unroll
    for (int kc = 0; kc < 4; kc++)
        qf[kc] = *(const bf16x8*)(Qrow + kc*32 + quad*8);

    floatx4 z[8] = {};
    float l_loc = 0.f;
    const int qg = q0w + lrow;                 // this lane's q row (swapped layout)

    const bfu* Kb = K + (size_t)b * SEQ * DM + h * DKH;
    const bfu* Vb = Vt + (size_t)(b * NH + h) * DKH * SEQ;
    const int ntiles = qt + 1;                 // 64-key tiles, causal

    for (int it = 0; it < ntiles; it++) {
        const int s0 = it * 64;
        __syncthreads();                       // prior iter's LDS reads done
        #pragma unroll
        for (int i = 0; i < 8; i++) {
            const int chunk = wave * 8 + i;    // wave-uniform
            if (chunk < 16) {
                const int kc = chunk >> 2, kg = chunk & 3;
                glds16(Kb + (size_t)(s0 + kg*16 + rowb) * DM + kc*32 + colb,
                       &Ks[kc][kg*16][0]);
            } else {
                const int c2 = chunk - 16;
                const int sh = c2 >> 3, dg = c2 & 7;
                glds16(Vb + (size_t)(dg*16 + rowb) * SEQ + s0 + sh*32 + colb,
                       &Vs[sh][dg*16][0]);
            }
        }
        __syncthreads();                       // staged data visible

        // ---- S^T = K Q^T : lane holds S[s=st*16+quad*4+r][q=lrow] ----
        floatx4 sc[4];
        #pragma unroll
        for (int st = 0; st < 4; st++) {
            floatx4 a = {};
            #pragma unroll
            for (int kc = 0; kc < 4; kc++) {
                bf16x8 kf = *(const bf16x8*)&Ks[kc][st*16 + lrow][quad*8];
                a = __builtin_amdgcn_mfma_f32_16x16x32_bf16(kf, qf[kc], a, 0, 0, 0);
            }
            sc[st] = a;
        }

        // ---- mask + exp + packed b64 store ----
        #pragma unroll
        for (int st = 0; st < 4; st++) {
            const int sbase = s0 + st*16 + quad*4;
            const float p0 = (sbase + 0 <= qg) ? __expf(sc[st][0]) : 0.f;
            const float p1 = (sbase + 1 <= qg) ? __expf(sc[st][1]) : 0.f;
            const float p2 = (sbase + 2 <= qg) ? __expf(sc[st][2]) : 0.f;
            const float p3 = (sbase + 3 <= qg) ? __expf(sc[st][3]) : 0.f;
            l_loc += (p0 + p1) + (p2 + p3);
            u32x2 pk;
            pk[0] = (unsigned)f2bf(p0) | ((unsigned)f2bf(p1) << 16);
            pk[1] = (unsigned)f2bf(p2) | ((unsigned)f2bf(p3) << 16);
            *(u32x2*)&Ps[wave][lrow][st*16 + quad*4] = pk;
        }

        // ---- O += P V ----
        bf16x8 pf0 = *(const bf16x8*)&Ps[wave][lrow][quad*8];
        bf16x8 pf1 = *(const bf16x8*)&Ps[wave][lrow][32 + quad*8];
        #pragma unroll
        for (int dt = 0; dt < 8; dt++) {
            bf16x8 v0 = *(const bf16x8*)&Vs[0][dt*16 + lrow][quad*8];
            z[dt] = __builtin_amdgcn_mfma_f32_16x16x32_bf16(pf0, v0, z[dt], 0, 0, 0);
            bf16x8 v1 = *(const bf16x8*)&Vs[1][dt*16 + lrow][quad*8];
            z[dt] = __builtin_amdgcn_mfma_f32_16x16x32_bf16(pf1, v1, z[dt], 0, 0, 0);
        }
    }

    // ---- final l reduce + normalize + store ----
    float L = l_loc;
    L += __shfl_xor(L, 16);
    L += __shfl_xor(L, 32);
    float inv[4];
    #pragma unroll
    for (int r = 0; r < 4; r++)
        inv[r] = 1.0f / __shfl(L, quad*4 + r, 64);
    #pragma unroll
    for (int dt = 0; dt < 8; dt++) {
        #pragma unroll
        for (int r = 0; r < 4; r++) {
            const int qq = q0w + quad*4 + r;
            const int dk = dt*16 + lrow;
            Z[(size_t)(b * SEQ + qq) * DM + h * DKH + dk] = f2bf(z[dt][r] * inv[r]);
        }
    }
}

// =====================================================================
// output projection (m97-style): out_f32 = Zb * WtO^T + bO — unchanged
// =====================================================================
__global__ __launch_bounds__(256)
void out_gemm(const bfu* __restrict__ Zb, const bfu* __restrict__ WtO,
              const float* __restrict__ bO, float* out) {
    __shared__ bfu As[128 * 32];
    __shared__ bfu Bs[128 * 32];
    const int tid  = threadIdx.x;
    const int lane = tid & 63;
    const int wave = tid >> 6;
    const int lrow = lane & 15;
    const int quad = lane >> 4;
    const int mw = (wave & 1) * 64;
    const int nw = (wave >> 1) * 64;
    const size_t m0 = (size_t)blockIdx.x * 128;
    const size_t n0 = (size_t)blockIdx.y * 128;
    const int rowb = lane >> 2, colb = (lane & 3) * 8;

    floatx4 acc[4][4] = {};

    for (int k0 = 0; k0 < DM; k0 += 32) {
        __syncthreads();
        #pragma unroll
        for (int i = 0; i < 2; i++) {
            const int rg = wave * 2 + i;
            glds16(Zb  + (m0 + rg*16 + rowb) * DM + k0 + colb, &As[rg * 512]);
            glds16(WtO + (n0 + rg*16 + rowb) * DM + k0 + colb, &Bs[rg * 512]);
        }
        __syncthreads();
        bf16x8 af[4], bfr[4];
        #pragma unroll
        for (int t = 0; t < 4; t++) {
            af[t]  = *(const bf16x8*)&As[(mw + t*16 + lrow) * 32 + quad * 8];
            bfr[t] = *(const bf16x8*)&Bs[(nw + t*16 + lrow) * 32 + quad * 8];
        }
        #pragma unroll
        for (int mt = 0; mt < 4; mt++)
            #pragma unroll
            for (int nt = 0; nt < 4; nt++)
                acc[mt][nt] = __builtin_amdgcn_mfma_f32_16x16x32_bf16(
                                  af[mt], bfr[nt], acc[mt][nt], 0, 0, 0);
    }

    #pragma unroll
    for (int mt = 0; mt < 4; mt++) {
        #pragma unroll
        for (int nt = 0; nt < 4; nt++) {
            const size_t gn = n0 + nw + nt*16 + lrow;
            const float bv = bO[gn];
            #pragma unroll
            for (int r = 0; r < 4; r++) {
                const size_t gm = m0 + mw + mt*16 + quad*4 + r;
                out[gm * DM + gn] = acc[mt][nt][r] + bv;
            }
        }
    }
}

// =====================================================================
extern "C" void kernel_launch(void* const* d_in, const int* in_sizes, int n_in,
                              void* d_out, int out_size, void* d_ws, size_t ws_size,
                              hipStream_t stream) {
    const float* x  = (const float*)d_in[0];
    const float* WQ = (const float*)d_in[1];
    const float* bQ = (const float*)d_in[2];
    const float* WK = (const float*)d_in[3];
    const float* bK = (const float*)d_in[4];
    const float* WV = (const float*)d_in[5];
    const float* bV = (const float*)d_in[6];
    const float* WO = (const float*)d_in[7];
    const float* bO = (const float*)d_in[8];
    float* out = (float*)d_out;
    bfu* ws  = (bfu*)d_ws;
    bfu* dob = (bfu*)d_out;   // d_out doubles as scratch before out_gemm writes it

    // ws (64 MiB = 33.55M bfu):
    //   ws0: Qall [4096][2048]  -> after flash: WtO [2048][2048]
    //   ws1: Kall [4096][2048]
    //   ws2: Vt   [2][16][128][2048]
    //   ws3: WtV (4.19M) -> after proj: Zb [4096][2048]
    // d_out (16.78M bfu) as early scratch:
    //   xb  = dob[0 .. 8.39M)          (bf16 x)
    //   WtQ = dob[8.39M .. 12.58M)
    //   WtK = dob[12.58M .. 16.78M)
    bfu* Qall = ws;
    bfu* Kall = Qall + 8388608;
    bfu* Vt   = Kall + 8388608;
    bfu* Zb   = Vt   + 8388608;
    bfu* WtV  = Zb;                     // dead before flash writes Zb
    bfu* xb   = dob;
    bfu* WtQ  = dob + 8388608;
    bfu* WtK  = dob + 12582912;

    const dim3 tb(32, 8, 1);

    cvt_x<<<8192, 256, 0, stream>>>(x, xb, BATCH * SEQ * DM);

    // fused weight transposes (Q scaled by 1/sqrt(128)) + fused QKV GEMM
    tcvt_qkv<<<dim3(4, 64, 48), tb, 0, stream>>>(WQ, WK, WV, WtQ, WtK, WtV);
    proj_qkv8<<<dim3(16, 24), 512, 0, stream>>>(xb, WtQ, WtK, WtV,
                                                bQ, bK, bV, Qall, Kall, Vt);

    flash_attn<<<dim3(32, 32), 256, 0, stream>>>(Qall, Kall, Vt, Zb);

    // Qall dead -> its region becomes WtO
    tcvt<<<dim3(64, 64, 1), tb, 0, stream>>>(WO, Qall, DM, DM, 1.0f);
    out_gemm<<<dim3(32, 16), 256, 0, stream>>>(Zb, Qall, bO, out);
}

// Round 3
// 364.783 us; speedup vs baseline: 1.0331x; 1.0331x over previous
//
#include <hip/hip_runtime.h>
#include <hip/hip_bf16.h>

// ---------- types ----------
typedef unsigned short bfu;                                        // bf16 bit-pattern storage
typedef short          bf16x8 __attribute__((ext_vector_type(8))); // MFMA A/B frag (4 VGPRs)
typedef float          floatx4 __attribute__((ext_vector_type(4)));// MFMA C/D frag
typedef unsigned short bfu4 __attribute__((ext_vector_type(4)));   // 8B packed store
typedef unsigned int   u32x2 __attribute__((ext_vector_type(2)));  // 8B LDS write

__device__ __forceinline__ bfu f2bf(float f) {
    __hip_bfloat16 h = __float2bfloat16(f);   // RNE
    return __builtin_bit_cast(unsigned short, h);
}

// async global->LDS, 16B per lane; lds base must be wave-uniform (HW adds lane*16)
__device__ __forceinline__ void glds16(const bfu* g, bfu* l) {
    __builtin_amdgcn_global_load_lds(
        (const __attribute__((address_space(1))) unsigned int*)g,
        (__attribute__((address_space(3))) unsigned int*)l, 16, 0, 0);
}

// ---------- problem constants ----------
#define BATCH 2
#define SEQ   2048
#define DM    2048
#define NH    16
#define DKH   128
#define SCALE 0.08838834764831845f   // 1/sqrt(128)

// =====================================================================
// convert x (f32) -> xb (bf16), 4 elems/thread
// =====================================================================
__global__ __launch_bounds__(256)
void cvt_x(const float* __restrict__ x, bfu* __restrict__ xb, int n) {
    const int i = (blockIdx.x * 256 + threadIdx.x) * 4;
    if (i >= n) return;
    const float4 v = *(const float4*)(x + i);
    bfu4 p; p[0] = f2bf(v.x); p[1] = f2bf(v.y); p[2] = f2bf(v.z); p[3] = f2bf(v.w);
    *(bfu4*)(xb + i) = p;
}

// =====================================================================
// batched transpose + f32->bf16 convert + scale (WO)
// =====================================================================
__global__ __launch_bounds__(256)
void tcvt(const float* __restrict__ in, bfu* __restrict__ out, int R, int C, float s) {
    __shared__ float tile[32][33];
    const int bz = blockIdx.z;
    const float* src = in + (size_t)bz * R * C;
    bfu* dst = out + (size_t)bz * R * C;
    const int c0 = blockIdx.x * 32, r0 = blockIdx.y * 32;
    const int tx = threadIdx.x, ty = threadIdx.y;
    #pragma unroll
    for (int i = 0; i < 4; i++)
        tile[ty + i*8][tx] = src[(size_t)(r0 + ty + i*8) * C + c0 + tx];
    __syncthreads();
    #pragma unroll
    for (int i = 0; i < 4; i++)
        dst[(size_t)(c0 + ty + i*8) * R + r0 + tx] = f2bf(tile[tx][ty + i*8] * s);
}

// =====================================================================
// fused Q/K/V weight transpose+convert: grid (4, 64, 48), block (32,8)
// =====================================================================
__global__ __launch_bounds__(256)
void tcvt_qkv(const float* __restrict__ WQ, const float* __restrict__ WK,
              const float* __restrict__ WV,
              bfu* __restrict__ WtQ, bfu* __restrict__ WtK, bfu* __restrict__ WtV) {
    __shared__ float tile[32][33];
    const int p  = blockIdx.z >> 4;
    const int bz = blockIdx.z & 15;
    const float* src = (p == 0) ? WQ : (p == 1) ? WK : WV;
    bfu*         dst = (p == 0) ? WtQ : (p == 1) ? WtK : WtV;
    const float  s   = (p == 0) ? SCALE : 1.0f;
    src += (size_t)bz * DM * DKH;
    dst += (size_t)bz * DM * DKH;
    const int c0 = blockIdx.x * 32, r0 = blockIdx.y * 32;
    const int tx = threadIdx.x, ty = threadIdx.y;
    #pragma unroll
    for (int i = 0; i < 4; i++)
        tile[ty + i*8][tx] = src[(size_t)(r0 + ty + i*8) * DKH + c0 + tx];
    __syncthreads();
    #pragma unroll
    for (int i = 0; i < 4; i++)
        dst[(size_t)(c0 + ty + i*8) * DM + r0 + tx] = f2bf(tile[tx][ty + i*8] * s);
}

// =====================================================================
// 8-phase 256x256 GEMM helpers (T2 st_16x32 swizzle, T3/T4 counted vmcnt,
// T5 setprio).  Half-tile = [128 rows][64 cols] bf16, stored as 16x32
// subtiles (1024B): elem(r,c) = ((r>>4)*2+(c>>5))*512 + (r&15)*32
//                               + ((c&31) ^ ((r&8)?16:0))
// Stage keeps the LDS dest LINEAR (global_load_lds) and inverse-swizzles
// the per-lane GLOBAL source; reader applies the same XOR -> identity.
// =====================================================================
__device__ __forceinline__ void stg_half(const bfu* gbase, bfu* slot,
                                         int wave, int lane, int csw) {
    #pragma unroll
    for (int l = 0; l < 2; l++) {
        const int j = l * 8 + wave;                         // wave-issue id 0..15
        glds16(gbase + (size_t)((j >> 1) * 16 + (lane >> 2)) * DM
                     + (j & 1) * 32 + csw,
               slot + j * 512);
    }
}

__device__ __forceinline__ void ld_b8(bf16x8 (&bv)[4][2], const bfu* slot, int rdo) {
    #pragma unroll
    for (int n = 0; n < 4; n++)
        #pragma unroll
        for (int ks = 0; ks < 2; ks++)
            bv[n][ks] = *(const bf16x8*)&slot[(n * 2 + ks) * 512 + rdo];
}

__device__ __forceinline__ void ld_a8(bf16x8 (&af)[4][2], const bfu* slot, int rdo) {
    #pragma unroll
    for (int m = 0; m < 4; m++)
        #pragma unroll
        for (int ks = 0; ks < 2; ks++)
            af[m][ks] = *(const bf16x8*)&slot[(m * 2 + ks) * 512 + rdo];
}

template<int MH, int NHALF>
__device__ __forceinline__ void mfma16(floatx4 (&acc)[8][4],
                                       const bf16x8 (&af)[4][2],
                                       const bf16x8 (&bv)[4][2]) {
    __builtin_amdgcn_s_setprio(1);
    #pragma unroll
    for (int m = 0; m < 4; m++)
        #pragma unroll
        for (int n = 0; n < 2; n++)
            #pragma unroll
            for (int ks = 0; ks < 2; ks++)
                acc[MH*4 + m][NHALF*2 + n] =
                    __builtin_amdgcn_mfma_f32_16x16x32_bf16(
                        af[m][ks], bv[NHALF*2 + n][ks],
                        acc[MH*4 + m][NHALF*2 + n], 0, 0, 0);
    __builtin_amdgcn_s_setprio(0);
}

#define BARW()                                                      \
    __builtin_amdgcn_s_barrier();                                   \
    asm volatile("s_waitcnt lgkmcnt(0)" ::: "memory");              \
    __builtin_amdgcn_sched_barrier(0)

// =====================================================================
// Q+K projection, 256^2 8-phase: grid (16, 16) = EXACTLY 256 blocks
// (one full round at 1 block/CU; V handled by proj_v to avoid the
// 384-block 75%-tail that cost R2 its win).
// by = p*8 + n-tile.  p 0: Q->Qall (scaled), 1: K->Kall
// =====================================================================
__global__ __launch_bounds__(512, 2)
void proj_qk8(const bfu* __restrict__ xb,
              const bfu* __restrict__ WtQ, const bfu* __restrict__ WtK,
              const float* __restrict__ bQ, const float* __restrict__ bK,
              bfu* __restrict__ Qall, bfu* __restrict__ Kall) {
    __shared__ __align__(16) bfu As[2][2][8192];   // [buf][half][128*64]
    __shared__ __align__(16) bfu Bs[2][2][8192];

    const int p = blockIdx.y >> 3;
    const bfu*   Wt   = (p == 0) ? WtQ : WtK;
    const float* bias = (p == 0) ? bQ  : bK;
    const float  bscale = (p == 0) ? SCALE : 1.0f;

    const int tid  = threadIdx.x;
    const int lane = tid & 63;
    const int wave = tid >> 6;
    const int lrow = lane & 15;
    const int quad = lane >> 4;
    const int wr   = wave >> 2;            // 0..1 : M half (128 rows)
    const int wc   = wave & 3;             // 0..3 : N quarter (64 cols)
    const size_t m0 = (size_t)blockIdx.x * 256;
    const int    n0 = (int)(blockIdx.y & 7) * 256;

    // stage: per-lane inverse-swizzled global col offset (elements)
    const int csw = ((lane & 3) * 8) ^ ((lane & 32) ? 16 : 0);
    // read: swizzled offset within a (16-row x 32-col) subtile pair
    const int rdo = lrow * 32 + ((quad * 8) ^ ((lrow & 8) ? 16 : 0));

    const bfu* Ab = xb + m0 * DM;
    const bfu* Bb = Wt + (size_t)n0 * DM;

    floatx4 acc[8][4] = {};
    bf16x8 af[4][2], bv[4][2];

#define STAGE_A(tau, h)                                                     \
    if ((tau) < 32) stg_half(Ab + (size_t)((h) * 128) * DM + (tau) * 64,    \
                             &As[(tau) & 1][h][0], wave, lane, csw)
#define STAGE_B(tau, h)                                                     \
    if ((tau) < 32) stg_half(Bb + (size_t)((h) * 128) * DM + (tau) * 64,    \
                             &Bs[(tau) & 1][h][0], wave, lane, csw)

    // ---- prologue: 7 half-tiles (K-tile 0 + 3/4 of K-tile 1) ----
    STAGE_B(0, 0); STAGE_B(0, 1); STAGE_A(0, 0); STAGE_A(0, 1);
    STAGE_B(1, 0); STAGE_B(1, 1); STAGE_A(1, 0);
    asm volatile("s_waitcnt vmcnt(6)" ::: "memory");
    __builtin_amdgcn_s_barrier();

    #pragma unroll 1
    for (int i = 0; i < 16; i++) {
        const int t0 = 2 * i;
        // ======== K-tile t0 (buf 0) ========
        ld_b8(bv, &Bs[0][wc >> 1][(wc & 1) * 4096], rdo);
        ld_a8(af, &As[0][wr][0], rdo);
        STAGE_A(t0 + 1, 1);
        BARW();
        mfma16<0, 0>(acc, af, bv);
        __builtin_amdgcn_s_barrier();
        STAGE_B(t0 + 2, 0);
        BARW();
        mfma16<0, 1>(acc, af, bv);
        __builtin_amdgcn_s_barrier();
        ld_a8(af, &As[0][wr][4096], rdo);
        STAGE_B(t0 + 2, 1);
        BARW();
        mfma16<1, 0>(acc, af, bv);
        __builtin_amdgcn_s_barrier();
        STAGE_A(t0 + 2, 0);
        BARW();
        mfma16<1, 1>(acc, af, bv);
        if (i == 15) asm volatile("s_waitcnt vmcnt(0)" ::: "memory");
        else         asm volatile("s_waitcnt vmcnt(6)" ::: "memory");
        __builtin_amdgcn_s_barrier();
        // ======== K-tile t0+1 (buf 1) ========
        ld_b8(bv, &Bs[1][wc >> 1][(wc & 1) * 4096], rdo);
        ld_a8(af, &As[1][wr][0], rdo);
        STAGE_A(t0 + 2, 1);
        BARW();
        mfma16<0, 0>(acc, af, bv);
        __builtin_amdgcn_s_barrier();
        STAGE_B(t0 + 3, 0);
        BARW();
        mfma16<0, 1>(acc, af, bv);
        __builtin_amdgcn_s_barrier();
        ld_a8(af, &As[1][wr][4096], rdo);
        STAGE_B(t0 + 3, 1);
        BARW();
        mfma16<1, 0>(acc, af, bv);
        __builtin_amdgcn_s_barrier();
        STAGE_A(t0 + 3, 0);
        BARW();
        mfma16<1, 1>(acc, af, bv);
        if (i < 15) asm volatile("s_waitcnt vmcnt(6)" ::: "memory");
        __builtin_amdgcn_s_barrier();
    }
#undef STAGE_A
#undef STAGE_B

    // ---- epilogue (C/D: col = lane&15 -> n, row = quad*4+r -> m) ----
    bfu* Out = (p == 0) ? Qall : Kall;
    #pragma unroll
    for (int m = 0; m < 8; m++) {
        #pragma unroll
        for (int n = 0; n < 4; n++) {
            const int gn = n0 + wc * 64 + n * 16 + lrow;
            const float bvv = bias[gn] * bscale;
            #pragma unroll
            for (int r = 0; r < 4; r++) {
                const size_t gm = m0 + wr * 128 + m * 16 + quad * 4 + r;
                Out[gm * DM + gn] = f2bf(acc[m][n][r] + bvv);
            }
        }
    }
}

// =====================================================================
// V projection, 2-phase 128^2 (m97-style; 512 blocks @ ~3/CU, no tail):
// Vt[b][h][dk][s] transposed epilogue.  grid (32,16), block 256
// =====================================================================
__global__ __launch_bounds__(256)
void proj_v(const bfu* __restrict__ xb, const bfu* __restrict__ WtV,
            const float* __restrict__ bV, bfu* __restrict__ Vt) {
    __shared__ bfu As[128 * 32];
    __shared__ bfu Bs[128 * 32];
    const int tid  = threadIdx.x;
    const int lane = tid & 63;
    const int wave = tid >> 6;
    const int lrow = lane & 15;
    const int quad = lane >> 4;
    const int mw = (wave & 1) * 64;
    const int nw = (wave >> 1) * 64;
    const size_t m0 = (size_t)blockIdx.x * 128;
    const size_t n0 = (size_t)blockIdx.y * 128;
    const int rowb = lane >> 2;          // 16-row group offset
    const int colb = (lane & 3) * 8;     // k-offset (elems)

    floatx4 acc[4][4] = {};

    for (int k0 = 0; k0 < DM; k0 += 32) {
        __syncthreads();
        #pragma unroll
        for (int i = 0; i < 2; i++) {
            const int rg = wave * 2 + i;    // 0..7 : 16-row groups
            glds16(xb  + (m0 + rg*16 + rowb) * DM + k0 + colb, &As[rg * 512]);
            glds16(WtV + (n0 + rg*16 + rowb) * DM + k0 + colb, &Bs[rg * 512]);
        }
        __syncthreads();
        bf16x8 af[4], bfr[4];
        #pragma unroll
        for (int t = 0; t < 4; t++) {
            af[t]  = *(const bf16x8*)&As[(mw + t*16 + lrow) * 32 + quad * 8];
            bfr[t] = *(const bf16x8*)&Bs[(nw + t*16 + lrow) * 32 + quad * 8];
        }
        #pragma unroll
        for (int mt = 0; mt < 4; mt++)
            #pragma unroll
            for (int nt = 0; nt < 4; nt++)
                acc[mt][nt] = __builtin_amdgcn_mfma_f32_16x16x32_bf16(
                                  af[mt], bfr[nt], acc[mt][nt], 0, 0, 0);
    }

    // transposed epilogue -> Vt[b][h][dk][s]
    #pragma unroll
    for (int mt = 0; mt < 4; mt++) {
        #pragma unroll
        for (int nt = 0; nt < 4; nt++) {
            const int nl = (int)n0 + nw + nt*16 + lrow;
            const float bvv = bV[nl];
            const size_t gm0 = m0 + mw + mt*16 + quad*4;   // 4 consecutive s rows
            const int b = (int)(gm0 >> 11), s = (int)(gm0 & 2047);
            bfu4 pk;
            #pragma unroll
            for (int r = 0; r < 4; r++) pk[r] = f2bf(acc[mt][nt][r] + bvv);
            *(bfu4*)&Vt[((size_t)(b * NH + (nl >> 7)) * DKH + (nl & 127)) * SEQ + s] = pk;
        }
    }
}

// =====================================================================
// causal flash attention (swapped QK^T, packed P-writes) — unchanged
// =====================================================================
__global__ __launch_bounds__(256)
void flash_attn(const bfu* __restrict__ Q, const bfu* __restrict__ K,
                const bfu* __restrict__ Vt, bfu* __restrict__ Z) {
    __shared__ bfu Ks[4][64][32];    // [kc][key][32 k-elems] : 16 KB, 64B rows
    __shared__ bfu Vs[2][128][32];   // [s-half][dk][32 s]    : 16 KB, 64B rows
    __shared__ bfu Ps[4][16][72];    // per wave [q][64 s + 8 pad] : 9 KB, 144B rows

    const int tid  = threadIdx.x;
    const int lane = tid & 63;
    const int wave = tid >> 6;
    const int lrow = lane & 15;
    const int quad = lane >> 4;
    const int hb = blockIdx.x;
    const int h = hb & 15, b = hb >> 4;
    const int qt = 31 - blockIdx.y;            // heavy blocks first
    const int q0w = qt * 64 + wave * 16;
    const int rowb = lane >> 2, colb = (lane & 3) * 8;

    const bfu* Qrow = Q + (size_t)(b * SEQ + q0w + lrow) * DM + h * DKH;
    bf16x8 qf[4];
    #pragma unroll
    for (int kc = 0; kc < 4; kc++)
        qf[kc] = *(const bf16x8*)(Qrow + kc*32 + quad*8);

    floatx4 z[8] = {};
    float l_loc = 0.f;
    const int qg = q0w + lrow;                 // this lane's q row (swapped layout)

    const bfu* Kb = K + (size_t)b * SEQ * DM + h * DKH;
    const bfu* Vb = Vt + (size_t)(b * NH + h) * DKH * SEQ;
    const int ntiles = qt + 1;                 // 64-key tiles, causal

    for (int it = 0; it < ntiles; it++) {
        const int s0 = it * 64;
        __syncthreads();                       // prior iter's LDS reads done
        #pragma unroll
        for (int i = 0; i < 8; i++) {
            const int chunk = wave * 8 + i;    // wave-uniform
            if (chunk < 16) {
                const int kc = chunk >> 2, kg = chunk & 3;
                glds16(Kb + (size_t)(s0 + kg*16 + rowb) * DM + kc*32 + colb,
                       &Ks[kc][kg*16][0]);
            } else {
                const int c2 = chunk - 16;
                const int sh = c2 >> 3, dg = c2 & 7;
                glds16(Vb + (size_t)(dg*16 + rowb) * SEQ + s0 + sh*32 + colb,
                       &Vs[sh][dg*16][0]);
            }
        }
        __syncthreads();                       // staged data visible

        // ---- S^T = K Q^T : lane holds S[s=st*16+quad*4+r][q=lrow] ----
        floatx4 sc[4];
        #pragma unroll
        for (int st = 0; st < 4; st++) {
            floatx4 a = {};
            #pragma unroll
            for (int kc = 0; kc < 4; kc++) {
                bf16x8 kf = *(const bf16x8*)&Ks[kc][st*16 + lrow][quad*8];
                a = __builtin_amdgcn_mfma_f32_16x16x32_bf16(kf, qf[kc], a, 0, 0, 0);
            }
            sc[st] = a;
        }

        // ---- mask + exp + packed b64 store ----
        #pragma unroll
        for (int st = 0; st < 4; st++) {
            const int sbase = s0 + st*16 + quad*4;
            const float p0 = (sbase + 0 <= qg) ? __expf(sc[st][0]) : 0.f;
            const float p1 = (sbase + 1 <= qg) ? __expf(sc[st][1]) : 0.f;
            const float p2 = (sbase + 2 <= qg) ? __expf(sc[st][2]) : 0.f;
            const float p3 = (sbase + 3 <= qg) ? __expf(sc[st][3]) : 0.f;
            l_loc += (p0 + p1) + (p2 + p3);
            u32x2 pk;
            pk[0] = (unsigned)f2bf(p0) | ((unsigned)f2bf(p1) << 16);
            pk[1] = (unsigned)f2bf(p2) | ((unsigned)f2bf(p3) << 16);
            *(u32x2*)&Ps[wave][lrow][st*16 + quad*4] = pk;
        }

        // ---- O += P V ----
        bf16x8 pf0 = *(const bf16x8*)&Ps[wave][lrow][quad*8];
        bf16x8 pf1 = *(const bf16x8*)&Ps[wave][lrow][32 + quad*8];
        #pragma unroll
        for (int dt = 0; dt < 8; dt++) {
            bf16x8 v0 = *(const bf16x8*)&Vs[0][dt*16 + lrow][quad*8];
            z[dt] = __builtin_amdgcn_mfma_f32_16x16x32_bf16(pf0, v0, z[dt], 0, 0, 0);
            bf16x8 v1 = *(const bf16x8*)&Vs[1][dt*16 + lrow][quad*8];
            z[dt] = __builtin_amdgcn_mfma_f32_16x16x32_bf16(pf1, v1, z[dt], 0, 0, 0);
        }
    }

    // ---- final l reduce + normalize + store ----
    float L = l_loc;
    L += __shfl_xor(L, 16);
    L += __shfl_xor(L, 32);
    float inv[4];
    #pragma unroll
    for (int r = 0; r < 4; r++)
        inv[r] = 1.0f / __shfl(L, quad*4 + r, 64);
    #pragma unroll
    for (int dt = 0; dt < 8; dt++) {
        #pragma unroll
        for (int r = 0; r < 4; r++) {
            const int qq = q0w + quad*4 + r;
            const int dk = dt*16 + lrow;
            Z[(size_t)(b * SEQ + qq) * DM + h * DKH + dk] = f2bf(z[dt][r] * inv[r]);
        }
    }
}

// =====================================================================
// output projection (m97-style): out_f32 = Zb * WtO^T + bO — unchanged
// =====================================================================
__global__ __launch_bounds__(256)
void out_gemm(const bfu* __restrict__ Zb, const bfu* __restrict__ WtO,
              const float* __restrict__ bO, float* out) {
    __shared__ bfu As[128 * 32];
    __shared__ bfu Bs[128 * 32];
    const int tid  = threadIdx.x;
    const int lane = tid & 63;
    const int wave = tid >> 6;
    const int lrow = lane & 15;
    const int quad = lane >> 4;
    const int mw = (wave & 1) * 64;
    const int nw = (wave >> 1) * 64;
    const size_t m0 = (size_t)blockIdx.x * 128;
    const size_t n0 = (size_t)blockIdx.y * 128;
    const int rowb = lane >> 2, colb = (lane & 3) * 8;

    floatx4 acc[4][4] = {};

    for (int k0 = 0; k0 < DM; k0 += 32) {
        __syncthreads();
        #pragma unroll
        for (int i = 0; i < 2; i++) {
            const int rg = wave * 2 + i;
            glds16(Zb  + (m0 + rg*16 + rowb) * DM + k0 + colb, &As[rg * 512]);
            glds16(WtO + (n0 + rg*16 + rowb) * DM + k0 + colb, &Bs[rg * 512]);
        }
        __syncthreads();
        bf16x8 af[4], bfr[4];
        #pragma unroll
        for (int t = 0; t < 4; t++) {
            af[t]  = *(const bf16x8*)&As[(mw + t*16 + lrow) * 32 + quad * 8];
            bfr[t] = *(const bf16x8*)&Bs[(nw + t*16 + lrow) * 32 + quad * 8];
        }
        #pragma unroll
        for (int mt = 0; mt < 4; mt++)
            #pragma unroll
            for (int nt = 0; nt < 4; nt++)
                acc[mt][nt] = __builtin_amdgcn_mfma_f32_16x16x32_bf16(
                                  af[mt], bfr[nt], acc[mt][nt], 0, 0, 0);
    }

    #pragma unroll
    for (int mt = 0; mt < 4; mt++) {
        #pragma unroll
        for (int nt = 0; nt < 4; nt++) {
            const size_t gn = n0 + nw + nt*16 + lrow;
            const float bv = bO[gn];
            #pragma unroll
            for (int r = 0; r < 4; r++) {
                const size_t gm = m0 + mw + mt*16 + quad*4 + r;
                out[gm * DM + gn] = acc[mt][nt][r] + bv;
            }
        }
    }
}

// =====================================================================
extern "C" void kernel_launch(void* const* d_in, const int* in_sizes, int n_in,
                              void* d_out, int out_size, void* d_ws, size_t ws_size,
                              hipStream_t stream) {
    const float* x  = (const float*)d_in[0];
    const float* WQ = (const float*)d_in[1];
    const float* bQ = (const float*)d_in[2];
    const float* WK = (const float*)d_in[3];
    const float* bK = (const float*)d_in[4];
    const float* WV = (const float*)d_in[5];
    const float* bV = (const float*)d_in[6];
    const float* WO = (const float*)d_in[7];
    const float* bO = (const float*)d_in[8];
    float* out = (float*)d_out;
    bfu* ws  = (bfu*)d_ws;
    bfu* dob = (bfu*)d_out;   // d_out doubles as scratch before out_gemm writes it

    // ws (64 MiB = 33.55M bfu):
    //   ws0: Qall [4096][2048]  -> after flash: WtO [2048][2048]
    //   ws1: Kall [4096][2048]
    //   ws2: Vt   [2][16][128][2048]
    //   ws3: WtV (4.19M) -> after proj: Zb [4096][2048]
    // d_out (16.78M bfu) as early scratch:
    //   xb  = dob[0 .. 8.39M)          (bf16 x)
    //   WtQ = dob[8.39M .. 12.58M)
    //   WtK = dob[12.58M .. 16.78M)
    bfu* Qall = ws;
    bfu* Kall = Qall + 8388608;
    bfu* Vt   = Kall + 8388608;
    bfu* Zb   = Vt   + 8388608;
    bfu* WtV  = Zb;                     // dead before flash writes Zb
    bfu* xb   = dob;
    bfu* WtQ  = dob + 8388608;
    bfu* WtK  = dob + 12582912;

    const dim3 tb(32, 8, 1);

    cvt_x<<<8192, 256, 0, stream>>>(x, xb, BATCH * SEQ * DM);

    // fused weight transposes (Q scaled by 1/sqrt(128))
    tcvt_qkv<<<dim3(4, 64, 48), tb, 0, stream>>>(WQ, WK, WV, WtQ, WtK, WtV);

    // Q+K: one clean 256-block 8-phase round; V: 2-phase 128^2 (512 blocks)
    proj_qk8<<<dim3(16, 16), 512, 0, stream>>>(xb, WtQ, WtK, bQ, bK, Qall, Kall);
    proj_v<<<dim3(32, 16), 256, 0, stream>>>(xb, WtV, bV, Vt);

    flash_attn<<<dim3(32, 32), 256, 0, stream>>>(Qall, Kall, Vt, Zb);

    // Qall dead -> its region becomes WtO
    tcvt<<<dim3(64, 64, 1), tb, 0, stream>>>(WO, Qall, DM, DM, 1.0f);
    out_gemm<<<dim3(32, 16), 256, 0, stream>>>(Zb, Qall, bO, out);
}

// Round 4
// 361.297 us; speedup vs baseline: 1.0431x; 1.0097x over previous
//
#include <hip/hip_runtime.h>
#include <hip/hip_bf16.h>

// ---------- types ----------
typedef unsigned short bfu;                                        // bf16 bit-pattern storage
typedef short          bf16x8 __attribute__((ext_vector_type(8))); // MFMA A/B frag (4 VGPRs)
typedef float          floatx4 __attribute__((ext_vector_type(4)));// MFMA C/D frag
typedef unsigned short bfu4 __attribute__((ext_vector_type(4)));   // 8B packed store
typedef unsigned int   u32x2 __attribute__((ext_vector_type(2)));  // 8B LDS write

__device__ __forceinline__ bfu f2bf(float f) {
    __hip_bfloat16 h = __float2bfloat16(f);   // RNE
    return __builtin_bit_cast(unsigned short, h);
}

// async global->LDS, 16B per lane; lds base must be wave-uniform (HW adds lane*16)
__device__ __forceinline__ void glds16(const bfu* g, bfu* l) {
    __builtin_amdgcn_global_load_lds(
        (const __attribute__((address_space(1))) unsigned int*)g,
        (__attribute__((address_space(3))) unsigned int*)l, 16, 0, 0);
}

// ---------- problem constants ----------
#define BATCH 2
#define SEQ   2048
#define DM    2048
#define NH    16
#define DKH   128
#define SCALE 0.08838834764831845f   // 1/sqrt(128)

// =====================================================================
// convert x (f32) -> xb (bf16), 4 elems/thread
// =====================================================================
__global__ __launch_bounds__(256)
void cvt_x(const float* __restrict__ x, bfu* __restrict__ xb, int n) {
    const int i = (blockIdx.x * 256 + threadIdx.x) * 4;
    if (i >= n) return;
    const float4 v = *(const float4*)(x + i);
    bfu4 p; p[0] = f2bf(v.x); p[1] = f2bf(v.y); p[2] = f2bf(v.z); p[3] = f2bf(v.w);
    *(bfu4*)(xb + i) = p;
}

// =====================================================================
// batched transpose + f32->bf16 convert + scale (WO)
// =====================================================================
__global__ __launch_bounds__(256)
void tcvt(const float* __restrict__ in, bfu* __restrict__ out, int R, int C, float s) {
    __shared__ float tile[32][33];
    const int bz = blockIdx.z;
    const float* src = in + (size_t)bz * R * C;
    bfu* dst = out + (size_t)bz * R * C;
    const int c0 = blockIdx.x * 32, r0 = blockIdx.y * 32;
    const int tx = threadIdx.x, ty = threadIdx.y;
    #pragma unroll
    for (int i = 0; i < 4; i++)
        tile[ty + i*8][tx] = src[(size_t)(r0 + ty + i*8) * C + c0 + tx];
    __syncthreads();
    #pragma unroll
    for (int i = 0; i < 4; i++)
        dst[(size_t)(c0 + ty + i*8) * R + r0 + tx] = f2bf(tile[tx][ty + i*8] * s);
}

// =====================================================================
// fused Q/K/V weight transpose+convert: grid (4, 64, 48), block (32,8)
// =====================================================================
__global__ __launch_bounds__(256)
void tcvt_qkv(const float* __restrict__ WQ, const float* __restrict__ WK,
              const float* __restrict__ WV,
              bfu* __restrict__ WtQ, bfu* __restrict__ WtK, bfu* __restrict__ WtV) {
    __shared__ float tile[32][33];
    const int p  = blockIdx.z >> 4;
    const int bz = blockIdx.z & 15;
    const float* src = (p == 0) ? WQ : (p == 1) ? WK : WV;
    bfu*         dst = (p == 0) ? WtQ : (p == 1) ? WtK : WtV;
    const float  s   = (p == 0) ? SCALE : 1.0f;
    src += (size_t)bz * DM * DKH;
    dst += (size_t)bz * DM * DKH;
    const int c0 = blockIdx.x * 32, r0 = blockIdx.y * 32;
    const int tx = threadIdx.x, ty = threadIdx.y;
    #pragma unroll
    for (int i = 0; i < 4; i++)
        tile[ty + i*8][tx] = src[(size_t)(r0 + ty + i*8) * DKH + c0 + tx];
    __syncthreads();
    #pragma unroll
    for (int i = 0; i < 4; i++)
        dst[(size_t)(c0 + ty + i*8) * DM + r0 + tx] = f2bf(tile[tx][ty + i*8] * s);
}

// =====================================================================
// 8-phase 256x256 GEMM helpers (T2 st_16x32 swizzle, T3/T4 counted vmcnt,
// T5 setprio).  Half-tile = [128 rows][64 cols] bf16, stored as 16x32
// subtiles (1024B): elem(r,c) = ((r>>4)*2+(c>>5))*512 + (r&15)*32
//                               + ((c&31) ^ ((r&8)?16:0))
// Stage keeps the LDS dest LINEAR (global_load_lds) and inverse-swizzles
// the per-lane GLOBAL source; reader applies the same XOR -> identity.
// =====================================================================
__device__ __forceinline__ void stg_half(const bfu* gbase, bfu* slot,
                                         int wave, int lane, int csw) {
    #pragma unroll
    for (int l = 0; l < 2; l++) {
        const int j = l * 8 + wave;                         // wave-issue id 0..15
        glds16(gbase + (size_t)((j >> 1) * 16 + (lane >> 2)) * DM
                     + (j & 1) * 32 + csw,
               slot + j * 512);
    }
}

__device__ __forceinline__ void ld_b8(bf16x8 (&bv)[4][2], const bfu* slot, int rdo) {
    #pragma unroll
    for (int n = 0; n < 4; n++)
        #pragma unroll
        for (int ks = 0; ks < 2; ks++)
            bv[n][ks] = *(const bf16x8*)&slot[(n * 2 + ks) * 512 + rdo];
}

__device__ __forceinline__ void ld_a8(bf16x8 (&af)[4][2], const bfu* slot, int rdo) {
    #pragma unroll
    for (int m = 0; m < 4; m++)
        #pragma unroll
        for (int ks = 0; ks < 2; ks++)
            af[m][ks] = *(const bf16x8*)&slot[(m * 2 + ks) * 512 + rdo];
}

template<int MH, int NHALF>
__device__ __forceinline__ void mfma16(floatx4 (&acc)[8][4],
                                       const bf16x8 (&af)[4][2],
                                       const bf16x8 (&bv)[4][2]) {
    __builtin_amdgcn_s_setprio(1);
    #pragma unroll
    for (int m = 0; m < 4; m++)
        #pragma unroll
        for (int n = 0; n < 2; n++)
            #pragma unroll
            for (int ks = 0; ks < 2; ks++)
                acc[MH*4 + m][NHALF*2 + n] =
                    __builtin_amdgcn_mfma_f32_16x16x32_bf16(
                        af[m][ks], bv[NHALF*2 + n][ks],
                        acc[MH*4 + m][NHALF*2 + n], 0, 0, 0);
    __builtin_amdgcn_s_setprio(0);
}

#define BARW()                                                      \
    __builtin_amdgcn_s_barrier();                                   \
    asm volatile("s_waitcnt lgkmcnt(0)" ::: "memory");              \
    __builtin_amdgcn_sched_barrier(0)

// =====================================================================
// Q+K projection, 256^2 8-phase: grid (16, 16) = EXACTLY 256 blocks
// (one full round at 1 block/CU).  by = p*8 + n-tile.  p 0:Q, 1:K
// =====================================================================
__global__ __launch_bounds__(512, 2)
void proj_qk8(const bfu* __restrict__ xb,
              const bfu* __restrict__ WtQ, const bfu* __restrict__ WtK,
              const float* __restrict__ bQ, const float* __restrict__ bK,
              bfu* __restrict__ Qall, bfu* __restrict__ Kall) {
    __shared__ __align__(16) bfu As[2][2][8192];   // [buf][half][128*64]
    __shared__ __align__(16) bfu Bs[2][2][8192];

    const int p = blockIdx.y >> 3;
    const bfu*   Wt   = (p == 0) ? WtQ : WtK;
    const float* bias = (p == 0) ? bQ  : bK;
    const float  bscale = (p == 0) ? SCALE : 1.0f;

    const int tid  = threadIdx.x;
    const int lane = tid & 63;
    const int wave = tid >> 6;
    const int lrow = lane & 15;
    const int quad = lane >> 4;
    const int wr   = wave >> 2;            // 0..1 : M half (128 rows)
    const int wc   = wave & 3;             // 0..3 : N quarter (64 cols)
    const size_t m0 = (size_t)blockIdx.x * 256;
    const int    n0 = (int)(blockIdx.y & 7) * 256;

    // stage: per-lane inverse-swizzled global col offset (elements)
    const int csw = ((lane & 3) * 8) ^ ((lane & 32) ? 16 : 0);
    // read: swizzled offset within a (16-row x 32-col) subtile pair
    const int rdo = lrow * 32 + ((quad * 8) ^ ((lrow & 8) ? 16 : 0));

    const bfu* Ab = xb + m0 * DM;
    const bfu* Bb = Wt + (size_t)n0 * DM;

    floatx4 acc[8][4] = {};
    bf16x8 af[4][2], bv[4][2];

#define STAGE_A(tau, h)                                                     \
    if ((tau) < 32) stg_half(Ab + (size_t)((h) * 128) * DM + (tau) * 64,    \
                             &As[(tau) & 1][h][0], wave, lane, csw)
#define STAGE_B(tau, h)                                                     \
    if ((tau) < 32) stg_half(Bb + (size_t)((h) * 128) * DM + (tau) * 64,    \
                             &Bs[(tau) & 1][h][0], wave, lane, csw)

    // ---- prologue: 7 half-tiles (K-tile 0 + 3/4 of K-tile 1) ----
    STAGE_B(0, 0); STAGE_B(0, 1); STAGE_A(0, 0); STAGE_A(0, 1);
    STAGE_B(1, 0); STAGE_B(1, 1); STAGE_A(1, 0);
    asm volatile("s_waitcnt vmcnt(6)" ::: "memory");
    __builtin_amdgcn_s_barrier();

    #pragma unroll 1
    for (int i = 0; i < 16; i++) {
        const int t0 = 2 * i;
        // ======== K-tile t0 (buf 0) ========
        ld_b8(bv, &Bs[0][wc >> 1][(wc & 1) * 4096], rdo);
        ld_a8(af, &As[0][wr][0], rdo);
        STAGE_A(t0 + 1, 1);
        BARW();
        mfma16<0, 0>(acc, af, bv);
        __builtin_amdgcn_s_barrier();
        STAGE_B(t0 + 2, 0);
        BARW();
        mfma16<0, 1>(acc, af, bv);
        __builtin_amdgcn_s_barrier();
        ld_a8(af, &As[0][wr][4096], rdo);
        STAGE_B(t0 + 2, 1);
        BARW();
        mfma16<1, 0>(acc, af, bv);
        __builtin_amdgcn_s_barrier();
        STAGE_A(t0 + 2, 0);
        BARW();
        mfma16<1, 1>(acc, af, bv);
        if (i == 15) asm volatile("s_waitcnt vmcnt(0)" ::: "memory");
        else         asm volatile("s_waitcnt vmcnt(6)" ::: "memory");
        __builtin_amdgcn_s_barrier();
        // ======== K-tile t0+1 (buf 1) ========
        ld_b8(bv, &Bs[1][wc >> 1][(wc & 1) * 4096], rdo);
        ld_a8(af, &As[1][wr][0], rdo);
        STAGE_A(t0 + 2, 1);
        BARW();
        mfma16<0, 0>(acc, af, bv);
        __builtin_amdgcn_s_barrier();
        STAGE_B(t0 + 3, 0);
        BARW();
        mfma16<0, 1>(acc, af, bv);
        __builtin_amdgcn_s_barrier();
        ld_a8(af, &As[1][wr][4096], rdo);
        STAGE_B(t0 + 3, 1);
        BARW();
        mfma16<1, 0>(acc, af, bv);
        __builtin_amdgcn_s_barrier();
        STAGE_A(t0 + 3, 0);
        BARW();
        mfma16<1, 1>(acc, af, bv);
        if (i < 15) asm volatile("s_waitcnt vmcnt(6)" ::: "memory");
        __builtin_amdgcn_s_barrier();
    }
#undef STAGE_A
#undef STAGE_B

    // ---- epilogue (C/D: col = lane&15 -> n, row = quad*4+r -> m) ----
    bfu* Out = (p == 0) ? Qall : Kall;
    #pragma unroll
    for (int m = 0; m < 8; m++) {
        #pragma unroll
        for (int n = 0; n < 4; n++) {
            const int gn = n0 + wc * 64 + n * 16 + lrow;
            const float bvv = bias[gn] * bscale;
            #pragma unroll
            for (int r = 0; r < 4; r++) {
                const size_t gm = m0 + wr * 128 + m * 16 + quad * 4 + r;
                Out[gm * DM + gn] = f2bf(acc[m][n][r] + bvv);
            }
        }
    }
}

// =====================================================================
// V projection, 2-phase 128^2 (m97-style; 512 blocks @ ~3/CU, no tail):
// Vt[b][h][dk][s] transposed epilogue.  grid (32,16), block 256
// =====================================================================
__global__ __launch_bounds__(256)
void proj_v(const bfu* __restrict__ xb, const bfu* __restrict__ WtV,
            const float* __restrict__ bV, bfu* __restrict__ Vt) {
    __shared__ bfu As[128 * 32];
    __shared__ bfu Bs[128 * 32];
    const int tid  = threadIdx.x;
    const int lane = tid & 63;
    const int wave = tid >> 6;
    const int lrow = lane & 15;
    const int quad = lane >> 4;
    const int mw = (wave & 1) * 64;
    const int nw = (wave >> 1) * 64;
    const size_t m0 = (size_t)blockIdx.x * 128;
    const size_t n0 = (size_t)blockIdx.y * 128;
    const int rowb = lane >> 2;          // 16-row group offset
    const int colb = (lane & 3) * 8;     // k-offset (elems)

    floatx4 acc[4][4] = {};

    for (int k0 = 0; k0 < DM; k0 += 32) {
        __syncthreads();
        #pragma unroll
        for (int i = 0; i < 2; i++) {
            const int rg = wave * 2 + i;    // 0..7 : 16-row groups
            glds16(xb  + (m0 + rg*16 + rowb) * DM + k0 + colb, &As[rg * 512]);
            glds16(WtV + (n0 + rg*16 + rowb) * DM + k0 + colb, &Bs[rg * 512]);
        }
        __syncthreads();
        bf16x8 af[4], bfr[4];
        #pragma unroll
        for (int t = 0; t < 4; t++) {
            af[t]  = *(const bf16x8*)&As[(mw + t*16 + lrow) * 32 + quad * 8];
            bfr[t] = *(const bf16x8*)&Bs[(nw + t*16 + lrow) * 32 + quad * 8];
        }
        #pragma unroll
        for (int mt = 0; mt < 4; mt++)
            #pragma unroll
            for (int nt = 0; nt < 4; nt++)
                acc[mt][nt] = __builtin_amdgcn_mfma_f32_16x16x32_bf16(
                                  af[mt], bfr[nt], acc[mt][nt], 0, 0, 0);
    }

    // transposed epilogue -> Vt[b][h][dk][s]
    #pragma unroll
    for (int mt = 0; mt < 4; mt++) {
        #pragma unroll
        for (int nt = 0; nt < 4; nt++) {
            const int nl = (int)n0 + nw + nt*16 + lrow;
            const float bvv = bV[nl];
            const size_t gm0 = m0 + mw + mt*16 + quad*4;   // 4 consecutive s rows
            const int b = (int)(gm0 >> 11), s = (int)(gm0 & 2047);
            bfu4 pk;
            #pragma unroll
            for (int r = 0; r < 4; r++) pk[r] = f2bf(acc[mt][nt][r] + bvv);
            *(bfu4*)&Vt[((size_t)(b * NH + (nl >> 7)) * DKH + (nl & 127)) * SEQ + s] = pk;
        }
    }
}

// =====================================================================
// causal flash attention, 64-key tiles, swapped QK^T.  NEW this round:
// K/V LDS sub-tiles use the proj_qk8-proven st_16x32 XOR swizzle
// (read chunk ^16 elems when row&8; staged via pre-swizzled global col)
// -- the identical 64B-row pattern WITHOUT the XOR measured 1.03e7 bank
// conflicts; proj_qkv8 WITH it measured 0.  grid (32 hb, 32 qt'), 256
// =====================================================================
__global__ __launch_bounds__(256)
void flash_attn(const bfu* __restrict__ Q, const bfu* __restrict__ K,
                const bfu* __restrict__ Vt, bfu* __restrict__ Z) {
    __shared__ bfu Ks[4][64][32];    // [kc][key][32 k-elems] : 16 KB, 64B rows
    __shared__ bfu Vs[2][128][32];   // [s-half][dk][32 s]    : 16 KB, 64B rows
    __shared__ bfu Ps[4][16][72];    // per wave [q][64 s + 8 pad] : 9 KB, 144B rows

    const int tid  = threadIdx.x;
    const int lane = tid & 63;
    const int wave = tid >> 6;
    const int lrow = lane & 15;
    const int quad = lane >> 4;
    const int hb = blockIdx.x;
    const int h = hb & 15, b = hb >> 4;
    const int qt = 31 - blockIdx.y;            // heavy blocks first
    const int q0w = qt * 64 + wave * 16;
    const int rowb = lane >> 2;
    // stage: inverse-swizzled global col (LDS row = lane>>2 -> row&8 = lane&32)
    const int csw  = ((lane & 3) * 8) ^ ((lane & 32) ? 16 : 0);
    // read: chunk selector XOR (row = **16 + lrow -> row&8 = lrow&8)
    const int xr   = (lrow & 8) ? 16 : 0;
    const int rq0  = (quad * 8) ^ xr;          // swizzled in-row chunk

    const bfu* Qrow = Q + (size_t)(b * SEQ + q0w + lrow) * DM + h * DKH;
    bf16x8 qf[4];
    #pragma unroll
    for (int kc = 0; kc < 4; kc++)
        qf[kc] = *(const bf16x8*)(Qrow + kc*32 + quad*8);

    floatx4 z[8] = {};
    float l_loc = 0.f;
    const int qg = q0w + lrow;                 // this lane's q row (swapped layout)

    const bfu* Kb = K + (size_t)b * SEQ * DM + h * DKH;
    const bfu* Vb = Vt + (size_t)(b * NH + h) * DKH * SEQ;
    const int ntiles = qt + 1;                 // 64-key tiles, causal

    for (int it = 0; it < ntiles; it++) {
        const int s0 = it * 64;
        __syncthreads();                       // prior iter's LDS reads done
        #pragma unroll
        for (int i = 0; i < 8; i++) {
            const int chunk = wave * 8 + i;    // wave-uniform
            if (chunk < 16) {
                const int kc = chunk >> 2, kg = chunk & 3;
                glds16(Kb + (size_t)(s0 + kg*16 + rowb) * DM + kc*32 + csw,
                       &Ks[kc][kg*16][0]);
            } else {
                const int c2 = chunk - 16;
                const int sh = c2 >> 3, dg = c2 & 7;
                glds16(Vb + (size_t)(dg*16 + rowb) * SEQ + s0 + sh*32 + csw,
                       &Vs[sh][dg*16][0]);
            }
        }
        __syncthreads();                       // staged data visible

        // ---- S^T = K Q^T : lane holds S[s=st*16+quad*4+r][q=lrow] ----
        floatx4 sc[4];
        #pragma unroll
        for (int st = 0; st < 4; st++) {
            floatx4 a = {};
            #pragma unroll
            for (int kc = 0; kc < 4; kc++) {
                bf16x8 kf = *(const bf16x8*)&Ks[kc][st*16 + lrow][rq0];
                a = __builtin_amdgcn_mfma_f32_16x16x32_bf16(kf, qf[kc], a, 0, 0, 0);
            }
            sc[st] = a;
        }

        // ---- mask + exp + packed b64 store ----
        #pragma unroll
        for (int st = 0; st < 4; st++) {
            const int sbase = s0 + st*16 + quad*4;
            const float p0 = (sbase + 0 <= qg) ? __expf(sc[st][0]) : 0.f;
            const float p1 = (sbase + 1 <= qg) ? __expf(sc[st][1]) : 0.f;
            const float p2 = (sbase + 2 <= qg) ? __expf(sc[st][2]) : 0.f;
            const float p3 = (sbase + 3 <= qg) ? __expf(sc[st][3]) : 0.f;
            l_loc += (p0 + p1) + (p2 + p3);
            u32x2 pk;
            pk[0] = (unsigned)f2bf(p0) | ((unsigned)f2bf(p1) << 16);
            pk[1] = (unsigned)f2bf(p2) | ((unsigned)f2bf(p3) << 16);
            *(u32x2*)&Ps[wave][lrow][st*16 + quad*4] = pk;
        }

        // ---- O += P V ----
        bf16x8 pf0 = *(const bf16x8*)&Ps[wave][lrow][quad*8];
        bf16x8 pf1 = *(const bf16x8*)&Ps[wave][lrow][32 + quad*8];
        #pragma unroll
        for (int dt = 0; dt < 8; dt++) {
            bf16x8 v0 = *(const bf16x8*)&Vs[0][dt*16 + lrow][rq0];
            z[dt] = __builtin_amdgcn_mfma_f32_16x16x32_bf16(pf0, v0, z[dt], 0, 0, 0);
            bf16x8 v1 = *(const bf16x8*)&Vs[1][dt*16 + lrow][rq0];
            z[dt] = __builtin_amdgcn_mfma_f32_16x16x32_bf16(pf1, v1, z[dt], 0, 0, 0);
        }
    }

    // ---- final l reduce + normalize + store ----
    float L = l_loc;
    L += __shfl_xor(L, 16);
    L += __shfl_xor(L, 32);
    float inv[4];
    #pragma unroll
    for (int r = 0; r < 4; r++)
        inv[r] = 1.0f / __shfl(L, quad*4 + r, 64);
    #pragma unroll
    for (int dt = 0; dt < 8; dt++) {
        #pragma unroll
        for (int r = 0; r < 4; r++) {
            const int qq = q0w + quad*4 + r;
            const int dk = dt*16 + lrow;
            Z[(size_t)(b * SEQ + qq) * DM + h * DKH + dk] = f2bf(z[dt][r] * inv[r]);
        }
    }
}

// =====================================================================
// output projection (m97-style): out_f32 = Zb * WtO^T + bO — unchanged
// =====================================================================
__global__ __launch_bounds__(256)
void out_gemm(const bfu* __restrict__ Zb, const bfu* __restrict__ WtO,
              const float* __restrict__ bO, float* out) {
    __shared__ bfu As[128 * 32];
    __shared__ bfu Bs[128 * 32];
    const int tid  = threadIdx.x;
    const int lane = tid & 63;
    const int wave = tid >> 6;
    const int lrow = lane & 15;
    const int quad = lane >> 4;
    const int mw = (wave & 1) * 64;
    const int nw = (wave >> 1) * 64;
    const size_t m0 = (size_t)blockIdx.x * 128;
    const size_t n0 = (size_t)blockIdx.y * 128;
    const int rowb = lane >> 2, colb = (lane & 3) * 8;

    floatx4 acc[4][4] = {};

    for (int k0 = 0; k0 < DM; k0 += 32) {
        __syncthreads();
        #pragma unroll
        for (int i = 0; i < 2; i++) {
            const int rg = wave * 2 + i;
            glds16(Zb  + (m0 + rg*16 + rowb) * DM + k0 + colb, &As[rg * 512]);
            glds16(WtO + (n0 + rg*16 + rowb) * DM + k0 + colb, &Bs[rg * 512]);
        }
        __syncthreads();
        bf16x8 af[4], bfr[4];
        #pragma unroll
        for (int t = 0; t < 4; t++) {
            af[t]  = *(const bf16x8*)&As[(mw + t*16 + lrow) * 32 + quad * 8];
            bfr[t] = *(const bf16x8*)&Bs[(nw + t*16 + lrow) * 32 + quad * 8];
        }
        #pragma unroll
        for (int mt = 0; mt < 4; mt++)
            #pragma unroll
            for (int nt = 0; nt < 4; nt++)
                acc[mt][nt] = __builtin_amdgcn_mfma_f32_16x16x32_bf16(
                                  af[mt], bfr[nt], acc[mt][nt], 0, 0, 0);
    }

    #pragma unroll
    for (int mt = 0; mt < 4; mt++) {
        #pragma unroll
        for (int nt = 0; nt < 4; nt++) {
            const size_t gn = n0 + nw + nt*16 + lrow;
            const float bv = bO[gn];
            #pragma unroll
            for (int r = 0; r < 4; r++) {
                const size_t gm = m0 + mw + mt*16 + quad*4 + r;
                out[gm * DM + gn] = acc[mt][nt][r] + bv;
            }
        }
    }
}

// =====================================================================
extern "C" void kernel_launch(void* const* d_in, const int* in_sizes, int n_in,
                              void* d_out, int out_size, void* d_ws, size_t ws_size,
                              hipStream_t stream) {
    const float* x  = (const float*)d_in[0];
    const float* WQ = (const float*)d_in[1];
    const float* bQ = (const float*)d_in[2];
    const float* WK = (const float*)d_in[3];
    const float* bK = (const float*)d_in[4];
    const float* WV = (const float*)d_in[5];
    const float* bV = (const float*)d_in[6];
    const float* WO = (const float*)d_in[7];
    const float* bO = (const float*)d_in[8];
    float* out = (float*)d_out;
    bfu* ws  = (bfu*)d_ws;
    bfu* dob = (bfu*)d_out;   // d_out doubles as scratch before out_gemm writes it

    // ws (64 MiB = 33.55M bfu):
    //   ws0: Qall [4096][2048]  -> after flash: WtO [2048][2048]
    //   ws1: Kall [4096][2048]
    //   ws2: Vt   [2][16][128][2048]
    //   ws3: WtV (4.19M) -> after proj: Zb [4096][2048]
    // d_out (16.78M bfu) as early scratch:
    //   xb  = dob[0 .. 8.39M)          (bf16 x)
    //   WtQ = dob[8.39M .. 12.58M)
    //   WtK = dob[12.58M .. 16.78M)
    bfu* Qall = ws;
    bfu* Kall = Qall + 8388608;
    bfu* Vt   = Kall + 8388608;
    bfu* Zb   = Vt   + 8388608;
    bfu* WtV  = Zb;                     // dead before flash writes Zb
    bfu* xb   = dob;
    bfu* WtQ  = dob + 8388608;
    bfu* WtK  = dob + 12582912;

    const dim3 tb(32, 8, 1);

    cvt_x<<<8192, 256, 0, stream>>>(x, xb, BATCH * SEQ * DM);

    // fused weight transposes (Q scaled by 1/sqrt(128))
    tcvt_qkv<<<dim3(4, 64, 48), tb, 0, stream>>>(WQ, WK, WV, WtQ, WtK, WtV);

    // Q+K: one clean 256-block 8-phase round; V: 2-phase 128^2 (512 blocks)
    proj_qk8<<<dim3(16, 16), 512, 0, stream>>>(xb, WtQ, WtK, bQ, bK, Qall, Kall);
    proj_v<<<dim3(32, 16), 256, 0, stream>>>(xb, WtV, bV, Vt);

    flash_attn<<<dim3(32, 32), 256, 0, stream>>>(Qall, Kall, Vt, Zb);

    // Qall dead -> its region becomes WtO
    tcvt<<<dim3(64, 64, 1), tb, 0, stream>>>(WO, Qall, DM, DM, 1.0f);
    out_gemm<<<dim3(32, 16), 256, 0, stream>>>(Zb, Qall, bO, out);
}